// Round 5
// baseline (4888.614 us; speedup 1.0000x reference)
//
#include <hip/hip_runtime.h>
#include <hip/hip_fp16.h>

typedef unsigned int u32;
typedef unsigned short u16;
typedef unsigned long long u64;

#define BB 64
#define TT 512
#define FF 128
#define HH 512
#define G4 2048  // 4*H

typedef _Float16 f16x8 __attribute__((ext_vector_type(8)));
typedef float f32x4 __attribute__((ext_vector_type(4)));

union UH2 { u32 u; __half2 h; };
__device__ inline __half2 u2h(u32 u) { UH2 t; t.u = u; return t.h; }

__device__ inline float sigm(float x) { return 1.0f / (1.0f + __expf(-x)); }
__device__ inline float tanh_fast(float x) { return 2.0f / (1.0f + __expf(-2.0f * x)) - 1.0f; }

// ---------------------------------------------------------------------------
// Zero BN accumulators and barrier flags (ws is poisoned before each call).
// ---------------------------------------------------------------------------
__global__ __launch_bounds__(256) void zero_init(float* __restrict__ accum, u32* __restrict__ cnt)
{
    int tid = threadIdx.x;
    for (int i = tid; i < 2048; i += 256) accum[i] = 0.0f;
    for (int i = tid; i < 2048; i += 256) cnt[i] = 0u;
}

// ---------------------------------------------------------------------------
// MFMA f16 GEMM: C(f16)[M,2048] = A[M,K] @ B[K,2048] + bias.
// BM=BN=128, BK=32, 256 threads (4 waves in 2x2), 4x4 16x16x32 tiles/wave.
// ---------------------------------------------------------------------------
template <bool A_HALF, bool AFFINE>
__global__ __launch_bounds__(256) void gemm_mfma(
    const void* __restrict__ Av, const float* __restrict__ Bw,
    const float* __restrict__ bias, const float* __restrict__ sc,
    const float* __restrict__ tr, __half* __restrict__ C, int K)
{
    __shared__ _Float16 sA[128 * 40];
    __shared__ _Float16 sB[128 * 40];
    const int tid = threadIdx.x;
    const int bn = blockIdx.x << 7;
    const int bm = blockIdx.y << 7;
    const int w = tid >> 6, l = tid & 63;
    const int mq = w >> 1, nq = w & 1;
    const int am = l & 15, kg = l >> 4;

    const _Float16* apb = sA + (mq * 64 + am) * 40 + kg * 8;
    const _Float16* bpb = sB + (nq * 64 + am) * 40 + kg * 8;

    const int ar = tid >> 1, akc = (tid & 1) * 16;
    const int bnn = tid & 127, bkr = (tid >> 7) * 16;

    f32x4 acc[4][4];
#pragma unroll
    for (int i = 0; i < 4; ++i)
#pragma unroll
        for (int j = 0; j < 4; ++j) acc[i][j] = (f32x4){0.f, 0.f, 0.f, 0.f};

    for (int k0 = 0; k0 < K; k0 += 32) {
        {
            float av[16];
            if constexpr (A_HALF) {
                const __half* Ap = (const __half*)Av + (size_t)(bm + ar) * K + k0 + akc;
                __half tmp[16];
                *(uint4*)&tmp[0] = *(const uint4*)Ap;
                *(uint4*)&tmp[8] = *(const uint4*)(Ap + 8);
#pragma unroll
                for (int i = 0; i < 16; ++i) av[i] = __half2float(tmp[i]);
            } else {
                const float* Ap = (const float*)Av + (size_t)(bm + ar) * K + k0 + akc;
#pragma unroll
                for (int i = 0; i < 16; i += 4) {
                    float4 v = *(const float4*)(Ap + i);
                    av[i] = v.x; av[i + 1] = v.y; av[i + 2] = v.z; av[i + 3] = v.w;
                }
            }
            if constexpr (AFFINE) {
#pragma unroll
                for (int i = 0; i < 16; ++i) av[i] = av[i] * sc[k0 + akc + i] + tr[k0 + akc + i];
            }
            _Float16 st[16];
#pragma unroll
            for (int i = 0; i < 16; ++i) st[i] = (_Float16)av[i];
            *(f16x8*)(sA + ar * 40 + akc) = *(f16x8*)&st[0];
            *(f16x8*)(sA + ar * 40 + akc + 8) = *(f16x8*)&st[8];
        }
        {
            _Float16 st[16];
#pragma unroll
            for (int i = 0; i < 16; ++i)
                st[i] = (_Float16)Bw[(size_t)(k0 + bkr + i) * G4 + bn + bnn];
            *(f16x8*)(sB + bnn * 40 + bkr) = *(f16x8*)&st[0];
            *(f16x8*)(sB + bnn * 40 + bkr + 8) = *(f16x8*)&st[8];
        }
        __syncthreads();
        f16x8 af[4], bf[4];
#pragma unroll
        for (int i = 0; i < 4; ++i) af[i] = *(const f16x8*)(apb + i * 16 * 40);
#pragma unroll
        for (int j = 0; j < 4; ++j) bf[j] = *(const f16x8*)(bpb + j * 16 * 40);
#pragma unroll
        for (int i = 0; i < 4; ++i)
#pragma unroll
            for (int j = 0; j < 4; ++j)
                acc[i][j] = __builtin_amdgcn_mfma_f32_16x16x32_f16(af[i], bf[j], acc[i][j], 0, 0, 0);
        __syncthreads();
    }

#pragma unroll
    for (int i = 0; i < 4; ++i) {
        const int row0 = bm + mq * 64 + i * 16 + kg * 4;
#pragma unroll
        for (int j = 0; j < 4; ++j) {
            const int col = bn + nq * 64 + j * 16 + am;
            const float bv = bias[col];
#pragma unroll
            for (int r = 0; r < 4; ++r) {
                float v = acc[i][j][r] + bv;
                u32 hu = (u32)__half_as_ushort(__float2half(v));
                u32 hn = __shfl_down(hu, 1);
                if ((am & 1) == 0) {
                    u32 pk = hu | (hn << 16);
                    *(u32*)(C + (size_t)(row0 + r) * G4 + col) = pk;
                }
            }
        }
    }
}

// ---------------------------------------------------------------------------
// MFMA LSTM scan v4: 256 threads (4 waves), weights in 256 VGPRs/lane,
// frag-major LDS h (conflict-free both directions), flag-array barrier.
// Grid: 32 blocks = 4 chains (bg) x 8 col-blocks (cb).
// Wave w = gate w, 64 hidden cols [cb*64, +64) in 4 col-groups of 16.
// Per step: poll 8 flags, acquire fence, gather h[16,512] from LLC into
// frag-major LDS (linear ds_write), 16 ds_read_b128 + 64 MFMA per wave,
// zbuf [m16][260] (free writes, float4 reads), 4 LSTM cells per thread,
// 8B agent h store, drain, one flag store. BN stats fused.
// ---------------------------------------------------------------------------
__global__ __launch_bounds__(256, 1) void lstm_scan_mfma(
    const __half* __restrict__ xW,   // [B*T, 2048] f16 (x@Wx + b)
    const float* __restrict__ Wh,    // [512, 2048] f32
    __half* __restrict__ hout,       // [B*T, 512] f16
    u32* __restrict__ flags,         // 32 flags x 32-u32 spacing
    float* __restrict__ accum)       // [sum 512][sumsq 512]
{
    __shared__ _Float16 shh[8192];     // 16 KB frag-major: chunk ci=kt*64+lane
    __shared__ float zbuf[16 * 260];   // 16.25 KB: z [m16][gc 256 +4]

    const int tid = threadIdx.x;
    const int cb = blockIdx.x & 7;
    const int bg = blockIdx.x >> 3;

    const int w = tid >> 6, l = tid & 63;
    const int am = l & 15, kq = l >> 4;

    // ---- one-time: wave w's gate-w weight cols -> 256 VGPRs per lane ----
    f16x8 bfr[4][16];
#pragma unroll
    for (int cg = 0; cg < 4; ++cg) {
        const int gcol = w * 512 + cb * 64 + cg * 16 + am;
#pragma unroll
        for (int kt = 0; kt < 16; ++kt) {
            _Float16 tmp[8];
#pragma unroll
            for (int j = 0; j < 8; ++j)
                tmp[j] = (_Float16)Wh[(size_t)(kt * 32 + kq * 8 + j) * G4 + gcol];
            bfr[cg][kt] = *(f16x8*)tmp;
        }
    }

    // update identity: thread owns (row ub, hcols uh4..uh4+3)
    const int ub = tid >> 4;
    const int t15 = tid & 15;
    const int uh4 = t15 * 4;
    const size_t growT = (size_t)(bg * 16 + ub) * TT;

    const u32* pollp = flags + (size_t)(bg * 8 + (l & 7)) * 32;
    u32* myflag = flags + (size_t)(bg * 8 + cb) * 32;

    float cst[4] = {0.f, 0.f, 0.f, 0.f};
    float ss[4] = {0.f, 0.f, 0.f, 0.f};
    float sq[4] = {0.f, 0.f, 0.f, 0.f};

    for (int t = 0; t < TT; ++t) {
        // xW prefetch: 4 gates x 4 hcols (uint2 each)
        const u32* xp = (const u32*)(xW + (growT + t) * G4 + cb * 64) + t15 * 2;
        uint2 xi = *(const uint2*)(xp);
        uint2 xf = *(const uint2*)(xp + 256);
        uint2 xg = *(const uint2*)(xp + 512);
        uint2 xo = *(const uint2*)(xp + 768);

        if (t > 0) {
            // ---- wait for all 8 col-blocks of this chain ----
            while (!__all((int)(__hip_atomic_load(pollp, __ATOMIC_RELAXED,
                                                  __HIP_MEMORY_SCOPE_AGENT) >= (u32)t))) {}
            __builtin_amdgcn_fence(__ATOMIC_ACQUIRE, "agent");

            // ---- gather h_{t-1}[16,512] -> frag-major LDS (linear writes) ----
#pragma unroll
            for (int hh = 0; hh < 4; ++hh) {
                int ci = hh * 256 + tid;
                int kt = ci >> 6, ll = ci & 63;
                int kqq = ll >> 4, amm = ll & 15;
                uint4 v = *(const uint4*)(hout +
                    ((size_t)(bg * 16 + amm) * TT + (t - 1)) * HH + (kt * 4 + kqq) * 8);
                *(uint4*)(shh + ci * 8) = v;
            }
            __syncthreads();

            // ---- MFMA: 4 col-group chains, A-frags read linearly ----
            f32x4 acc[4];
#pragma unroll
            for (int cg = 0; cg < 4; ++cg) acc[cg] = (f32x4){0.f, 0.f, 0.f, 0.f};
#pragma unroll
            for (int kt = 0; kt < 16; ++kt) {
                f16x8 av = *(const f16x8*)(shh + kt * 512 + l * 8);
#pragma unroll
                for (int cg = 0; cg < 4; ++cg)
                    acc[cg] = __builtin_amdgcn_mfma_f32_16x16x32_f16(av, bfr[cg][kt], acc[cg], 0, 0, 0);
            }
#pragma unroll
            for (int cg = 0; cg < 4; ++cg)
#pragma unroll
                for (int r = 0; r < 4; ++r)
                    zbuf[(kq * 4 + r) * 260 + w * 64 + cg * 16 + am] = acc[cg][r];
            __syncthreads();
        }

        // ---- gate update: 4 cells per thread ----
        float zi[4], zf[4], zg[4], zo[4];
        {
            __half2 p;
            p = u2h(xi.x); zi[0] = __low2float(p); zi[1] = __high2float(p);
            p = u2h(xi.y); zi[2] = __low2float(p); zi[3] = __high2float(p);
            p = u2h(xf.x); zf[0] = __low2float(p); zf[1] = __high2float(p);
            p = u2h(xf.y); zf[2] = __low2float(p); zf[3] = __high2float(p);
            p = u2h(xg.x); zg[0] = __low2float(p); zg[1] = __high2float(p);
            p = u2h(xg.y); zg[2] = __low2float(p); zg[3] = __high2float(p);
            p = u2h(xo.x); zo[0] = __low2float(p); zo[1] = __high2float(p);
            p = u2h(xo.y); zo[2] = __low2float(p); zo[3] = __high2float(p);
        }
        if (t > 0) {
            const float* zr = zbuf + ub * 260 + uh4;
            float4 vi = *(const float4*)(zr);
            float4 vf = *(const float4*)(zr + 64);
            float4 vg = *(const float4*)(zr + 128);
            float4 vo = *(const float4*)(zr + 192);
            zi[0] += vi.x; zi[1] += vi.y; zi[2] += vi.z; zi[3] += vi.w;
            zf[0] += vf.x; zf[1] += vf.y; zf[2] += vf.z; zf[3] += vf.w;
            zg[0] += vg.x; zg[1] += vg.y; zg[2] += vg.z; zg[3] += vg.w;
            zo[0] += vo.x; zo[1] += vo.y; zo[2] += vo.z; zo[3] += vo.w;
        }
        u16 hq[4];
#pragma unroll
        for (int j = 0; j < 4; ++j) {
            float ii = sigm(zi[j]), ff = sigm(zf[j]), gg = tanh_fast(zg[j]), oo = sigm(zo[j]);
            cst[j] = ff * cst[j] + ii * gg;
            float hv = oo * tanh_fast(cst[j]);
            ss[j] += hv; sq[j] += hv * hv;
            hq[j] = __half_as_ushort(__float2half(hv));
        }
        u64 pk = (u64)hq[0] | ((u64)hq[1] << 16) | ((u64)hq[2] << 32) | ((u64)hq[3] << 48);
        __hip_atomic_store((u64*)(hout + (growT + t) * HH + cb * 64 + uh4), pk,
                           __ATOMIC_RELAXED, __HIP_MEMORY_SCOPE_AGENT);

        __syncthreads();   // all waves drain vmcnt -> h visible at LLC
        if (tid == 0)
            __hip_atomic_store(myflag, (u32)(t + 1), __ATOMIC_RELAXED, __HIP_MEMORY_SCOPE_AGENT);
    }

    // ---- fused BN stats ----
    float* red = zbuf;
#pragma unroll
    for (int j = 0; j < 4; ++j) red[ub * 64 + uh4 + j] = ss[j];
    __syncthreads();
    if (tid < 64) {
        float s = 0.f;
#pragma unroll
        for (int b = 0; b < 16; ++b) s += red[b * 64 + tid];
        atomicAdd(&accum[cb * 64 + tid], s);
    }
    __syncthreads();
#pragma unroll
    for (int j = 0; j < 4; ++j) red[ub * 64 + uh4 + j] = sq[j];
    __syncthreads();
    if (tid < 64) {
        float s = 0.f;
#pragma unroll
        for (int b = 0; b < 16; ++b) s += red[b * 64 + tid];
        atomicAdd(&accum[HH + cb * 64 + tid], s);
    }
}

__global__ __launch_bounds__(512) void bn_finalize(
    const float* __restrict__ accum, const float* __restrict__ gamma,
    const float* __restrict__ beta, float* __restrict__ s, float* __restrict__ t)
{
    int j = threadIdx.x;
    const float inv = 1.0f / (float)(BB * TT);
    float m = accum[j] * inv;
    float v = accum[HH + j] * inv - m * m;
    float scv = gamma[j] * rsqrtf(v + 1e-5f);
    s[j] = scv;
    t[j] = beta[j] - m * scv;
}

// ---------------------------------------------------------------------------
// Head: out[m] = relu(bn(h2[m,:]) @ Wd1 + bd1) @ Wd2 + bd2
// ---------------------------------------------------------------------------
__global__ __launch_bounds__(256) void head_kernel(
    const __half* __restrict__ h2, const float* __restrict__ s2,
    const float* __restrict__ t2, const float* __restrict__ Wd1,
    const float* __restrict__ bd1, const float* __restrict__ Wd2,
    const float* __restrict__ bd2, float* __restrict__ out)
{
    const int tid = threadIdx.x;
    const int j = tid & 15;
    const int row = blockIdx.x * 16 + (tid >> 4);
    const __half* hr = h2 + (size_t)row * HH;
    float acc = 0.0f;
    for (int k = 0; k < HH; ++k) {
        float a = __half2float(hr[k]) * s2[k] + t2[k];
        acc += a * Wd1[k * 16 + j];
    }
    float r = fmaxf(acc + bd1[j], 0.0f);
    float v = r * Wd2[j];
#pragma unroll
    for (int off = 8; off; off >>= 1) v += __shfl_down(v, off, 16);
    if (j == 0) out[row] = v + bd2[0];
}

// ---------------------------------------------------------------------------
extern "C" void kernel_launch(void* const* d_in, const int* in_sizes, int n_in,
                              void* d_out, int out_size, void* d_ws, size_t ws_size,
                              hipStream_t stream)
{
    const float* x   = (const float*)d_in[0];
    const float* Wx1 = (const float*)d_in[1];
    const float* Wh1 = (const float*)d_in[2];
    const float* b1  = (const float*)d_in[3];
    const float* g1  = (const float*)d_in[4];
    const float* be1 = (const float*)d_in[5];
    const float* Wx2 = (const float*)d_in[6];
    const float* Wh2 = (const float*)d_in[7];
    const float* b2  = (const float*)d_in[8];
    const float* g2  = (const float*)d_in[9];
    const float* be2 = (const float*)d_in[10];
    const float* Wd1 = (const float*)d_in[11];
    const float* bd1 = (const float*)d_in[12];
    const float* Wd2 = (const float*)d_in[13];
    const float* bd2 = (const float*)d_in[14];
    float* out = (float*)d_out;

    char* ws = (char*)d_ws;
    __half* xW    = (__half*)(ws);                   // 128 MiB  [B*T, 2048]
    __half* h1    = (__half*)(ws + 134217728);       // 32 MiB   [B*T, 512]
    __half* h2    = (__half*)(ws + 167772160);       // 32 MiB
    float*  accum = (float*) (ws + 201326592);       // 2048 f32
    u32*    cnt   = (u32*)   (ws + 201334784);       // 2048 u32 barrier flags
    float*  s1    = (float*) (ws + 201342976);
    float*  t1    = s1 + HH;
    float*  s2    = t1 + HH;
    float*  t2    = s2 + HH;

    const int M = BB * TT;  // 32768

    zero_init<<<1, 256, 0, stream>>>(accum, cnt);

    gemm_mfma<false, false><<<dim3(16, M / 128), 256, 0, stream>>>(
        x, Wx1, b1, nullptr, nullptr, xW, FF);

    lstm_scan_mfma<<<32, 256, 0, stream>>>(xW, Wh1, h1, cnt, accum);
    bn_finalize<<<1, 512, 0, stream>>>(accum, g1, be1, s1, t1);

    gemm_mfma<true, true><<<dim3(16, M / 128), 256, 0, stream>>>(
        h1, Wx2, b2, s1, t1, xW, HH);

    lstm_scan_mfma<<<32, 256, 0, stream>>>(xW, Wh2, h2, cnt + 1024, accum + 1024);
    bn_finalize<<<1, 512, 0, stream>>>(accum + 1024, g2, be2, s2, t2);

    head_kernel<<<M / 16, 256, 0, stream>>>(h2, s2, t2, Wd1, bd1, Wd2, bd2, out);
}

// Round 6
// 3860.199 us; speedup vs baseline: 1.2664x; 1.2664x over previous
//
#include <hip/hip_runtime.h>
#include <hip/hip_fp16.h>

typedef unsigned int u32;
typedef unsigned short u16;
typedef unsigned long long u64;

#define BB 64
#define TT 512
#define FF 128
#define HH 512
#define G4 2048  // 4*H

typedef _Float16 f16x8 __attribute__((ext_vector_type(8)));
typedef float f32x4 __attribute__((ext_vector_type(4)));

union UH2 { u32 u; __half2 h; };
__device__ inline __half2 u2h(u32 u) { UH2 t; t.u = u; return t.h; }

__device__ inline float sigm(float x) { return 1.0f / (1.0f + __expf(-x)); }
__device__ inline float tanh_fast(float x) { return 2.0f / (1.0f + __expf(-2.0f * x)) - 1.0f; }

// ---------------------------------------------------------------------------
// Zero BN accumulators and barrier flags (ws is poisoned before each call).
// ---------------------------------------------------------------------------
__global__ __launch_bounds__(256) void zero_init(float* __restrict__ accum, u32* __restrict__ cnt)
{
    int tid = threadIdx.x;
    for (int i = tid; i < 2048; i += 256) accum[i] = 0.0f;
    for (int i = tid; i < 2048; i += 256) cnt[i] = 0u;
}

// ---------------------------------------------------------------------------
// MFMA f16 GEMM: C(f16)[M,2048] = A[M,K] @ B[K,2048] + bias.
// BM=BN=128, BK=32, 256 threads (4 waves in 2x2), 4x4 16x16x32 tiles/wave.
// ---------------------------------------------------------------------------
template <bool A_HALF, bool AFFINE>
__global__ __launch_bounds__(256) void gemm_mfma(
    const void* __restrict__ Av, const float* __restrict__ Bw,
    const float* __restrict__ bias, const float* __restrict__ sc,
    const float* __restrict__ tr, __half* __restrict__ C, int K)
{
    __shared__ _Float16 sA[128 * 40];
    __shared__ _Float16 sB[128 * 40];
    const int tid = threadIdx.x;
    const int bn = blockIdx.x << 7;
    const int bm = blockIdx.y << 7;
    const int w = tid >> 6, l = tid & 63;
    const int mq = w >> 1, nq = w & 1;
    const int am = l & 15, kg = l >> 4;

    const _Float16* apb = sA + (mq * 64 + am) * 40 + kg * 8;
    const _Float16* bpb = sB + (nq * 64 + am) * 40 + kg * 8;

    const int ar = tid >> 1, akc = (tid & 1) * 16;
    const int bnn = tid & 127, bkr = (tid >> 7) * 16;

    f32x4 acc[4][4];
#pragma unroll
    for (int i = 0; i < 4; ++i)
#pragma unroll
        for (int j = 0; j < 4; ++j) acc[i][j] = (f32x4){0.f, 0.f, 0.f, 0.f};

    for (int k0 = 0; k0 < K; k0 += 32) {
        {
            float av[16];
            if constexpr (A_HALF) {
                const __half* Ap = (const __half*)Av + (size_t)(bm + ar) * K + k0 + akc;
                __half tmp[16];
                *(uint4*)&tmp[0] = *(const uint4*)Ap;
                *(uint4*)&tmp[8] = *(const uint4*)(Ap + 8);
#pragma unroll
                for (int i = 0; i < 16; ++i) av[i] = __half2float(tmp[i]);
            } else {
                const float* Ap = (const float*)Av + (size_t)(bm + ar) * K + k0 + akc;
#pragma unroll
                for (int i = 0; i < 16; i += 4) {
                    float4 v = *(const float4*)(Ap + i);
                    av[i] = v.x; av[i + 1] = v.y; av[i + 2] = v.z; av[i + 3] = v.w;
                }
            }
            if constexpr (AFFINE) {
#pragma unroll
                for (int i = 0; i < 16; ++i) av[i] = av[i] * sc[k0 + akc + i] + tr[k0 + akc + i];
            }
            _Float16 st[16];
#pragma unroll
            for (int i = 0; i < 16; ++i) st[i] = (_Float16)av[i];
            *(f16x8*)(sA + ar * 40 + akc) = *(f16x8*)&st[0];
            *(f16x8*)(sA + ar * 40 + akc + 8) = *(f16x8*)&st[8];
        }
        {
            _Float16 st[16];
#pragma unroll
            for (int i = 0; i < 16; ++i)
                st[i] = (_Float16)Bw[(size_t)(k0 + bkr + i) * G4 + bn + bnn];
            *(f16x8*)(sB + bnn * 40 + bkr) = *(f16x8*)&st[0];
            *(f16x8*)(sB + bnn * 40 + bkr + 8) = *(f16x8*)&st[8];
        }
        __syncthreads();
        f16x8 af[4], bf[4];
#pragma unroll
        for (int i = 0; i < 4; ++i) af[i] = *(const f16x8*)(apb + i * 16 * 40);
#pragma unroll
        for (int j = 0; j < 4; ++j) bf[j] = *(const f16x8*)(bpb + j * 16 * 40);
#pragma unroll
        for (int i = 0; i < 4; ++i)
#pragma unroll
            for (int j = 0; j < 4; ++j)
                acc[i][j] = __builtin_amdgcn_mfma_f32_16x16x32_f16(af[i], bf[j], acc[i][j], 0, 0, 0);
        __syncthreads();
    }

#pragma unroll
    for (int i = 0; i < 4; ++i) {
        const int row0 = bm + mq * 64 + i * 16 + kg * 4;
#pragma unroll
        for (int j = 0; j < 4; ++j) {
            const int col = bn + nq * 64 + j * 16 + am;
            const float bv = bias[col];
#pragma unroll
            for (int r = 0; r < 4; ++r) {
                float v = acc[i][j][r] + bv;
                u32 hu = (u32)__half_as_ushort(__float2half(v));
                u32 hn = __shfl_down(hu, 1);
                if ((am & 1) == 0) {
                    u32 pk = hu | (hn << 16);
                    *(u32*)(C + (size_t)(row0 + r) * G4 + col) = pk;
                }
            }
        }
    }
}

// ---------------------------------------------------------------------------
// MFMA LSTM scan v5: 512 threads (8 waves, 2/SIMD), weights in 128 VGPR/lane,
// frag-major LDS h (linear both directions), fence-free bypass gather.
// Grid: 32 blocks = 4 chains (bg) x 8 col-blocks (cb).
// Wave w: gate w>>1, half (w&1)*32, i.e. 32 gatecols in 2 col-groups of 16.
// Protocol per step: poll 8 flags (sc1 loads), NO fence; gather h via
// agent-scope relaxed u64 loads (cache-bypass, LLC-fresh since producers
// drained sc1 stores before flag); LDS frag-major; 32 MFMA/wave; zbuf;
// update (2 cells/thread); sc1 h store; syncthreads drain; flag store.
// No L2 invalidation anywhere -> xW stream stays cached. BN stats fused.
// ---------------------------------------------------------------------------
__global__ __launch_bounds__(512, 2) void lstm_scan_mfma(
    const __half* __restrict__ xW,   // [B*T, 2048] f16 (x@Wx + b)
    const float* __restrict__ Wh,    // [512, 2048] f32
    __half* __restrict__ hout,       // [B*T, 512] f16
    u32* __restrict__ flags,         // flags x 32-u32 spacing
    float* __restrict__ accum)       // [sum 512][sumsq 512]
{
    __shared__ _Float16 shh[8192];     // 16 KB frag-major: chunk ci=kt*64+kq*16+row
    __shared__ float zbuf[16 * 260];   // 16.25 KB: z [m16][gc 256 +4]

    const int tid = threadIdx.x;
    const int cb = blockIdx.x & 7;
    const int bg = blockIdx.x >> 3;

    const int w = tid >> 6, l = tid & 63;
    const int am = l & 15, kq = l >> 4;

    // ---- one-time: wave's 32 Wh gate-cols -> 128 VGPRs per lane ----
    f16x8 bfr[2][16];
#pragma unroll
    for (int cg = 0; cg < 2; ++cg) {
        const int gcol = (w >> 1) * 512 + cb * 64 + (w & 1) * 32 + cg * 16 + am;
#pragma unroll
        for (int kt = 0; kt < 16; ++kt) {
            _Float16 tmp[8];
#pragma unroll
            for (int j = 0; j < 8; ++j)
                tmp[j] = (_Float16)Wh[(size_t)(kt * 32 + kq * 8 + j) * G4 + gcol];
            bfr[cg][kt] = *(f16x8*)tmp;
        }
    }

    // update identity: thread owns (row ub, hcols 2uh, 2uh+1)
    const int ub = tid >> 5, uh = tid & 31;
    const size_t growT = (size_t)(bg * 16 + ub) * TT;

    const u32* pollp = flags + (size_t)(bg * 8 + (l & 7)) * 32;
    u32* myflag = flags + (size_t)(bg * 8 + cb) * 32;

    // gather identity: 2 chunks of 16B per thread, frag-major ci = hh*512+tid
    //   ci -> kt=ci>>6, kq2=(ci>>4)&3, row=ci&15
    float cst0 = 0.f, cst1 = 0.f;
    float ss0 = 0.f, ss1 = 0.f, sq0 = 0.f, sq1 = 0.f;

    for (int t = 0; t < TT; ++t) {
        // xW prefetch: 4 gates x packed pair (stays cached in L1/L2 now)
        const u32* xp = (const u32*)(xW + (growT + t) * G4) + cb * 32 + uh;
        u32 xi = xp[0], xf = xp[256], xg = xp[512], xo = xp[768];

        if (t > 0) {
            // ---- wait for all 8 col-blocks of this chain (no fence needed) ----
            while (!__all((int)(__hip_atomic_load(pollp, __ATOMIC_RELAXED,
                                                  __HIP_MEMORY_SCOPE_AGENT) >= (u32)t))) {}

            // ---- gather h_{t-1}[16,512] via bypass loads -> frag-major LDS ----
#pragma unroll
            for (int hh = 0; hh < 2; ++hh) {
                int ci = hh * 512 + tid;
                int kt = ci >> 6, kq2 = (ci >> 4) & 3, row = ci & 15;
                const u64* src = (const u64*)(hout +
                    ((size_t)(bg * 16 + row) * TT + (t - 1)) * HH + (kt * 4 + kq2) * 8);
                u64 lo = __hip_atomic_load(src, __ATOMIC_RELAXED, __HIP_MEMORY_SCOPE_AGENT);
                u64 hi = __hip_atomic_load(src + 1, __ATOMIC_RELAXED, __HIP_MEMORY_SCOPE_AGENT);
                u64 pk[2] = {lo, hi};
                *(uint4*)(shh + ci * 8) = *(uint4*)pk;
            }
            __syncthreads();

            // ---- MFMA: 2 col-group chains, linear A-frag reads ----
            f32x4 a0 = {0.f, 0.f, 0.f, 0.f}, a1 = {0.f, 0.f, 0.f, 0.f};
#pragma unroll
            for (int kt = 0; kt < 16; ++kt) {
                f16x8 av = *(const f16x8*)(shh + kt * 512 + l * 8);
                a0 = __builtin_amdgcn_mfma_f32_16x16x32_f16(av, bfr[0][kt], a0, 0, 0, 0);
                a1 = __builtin_amdgcn_mfma_f32_16x16x32_f16(av, bfr[1][kt], a1, 0, 0, 0);
            }
            const int zc = (w >> 1) * 64 + (w & 1) * 32 + am;
#pragma unroll
            for (int r = 0; r < 4; ++r) {
                zbuf[(kq * 4 + r) * 260 + zc] = a0[r];
                zbuf[(kq * 4 + r) * 260 + zc + 16] = a1[r];
            }
            __syncthreads();
        }

        // ---- gate update: 2 cells per thread ----
        __half2 hxi = u2h(xi), hxf = u2h(xf), hxg = u2h(xg), hxo = u2h(xo);
        float zi0 = __low2float(hxi), zi1 = __high2float(hxi);
        float zf0 = __low2float(hxf), zf1 = __high2float(hxf);
        float zg0 = __low2float(hxg), zg1 = __high2float(hxg);
        float zo0 = __low2float(hxo), zo1 = __high2float(hxo);
        if (t > 0) {
            const float* zr = zbuf + ub * 260 + 2 * uh;
            zi0 += zr[0];   zi1 += zr[1];
            zf0 += zr[64];  zf1 += zr[65];
            zg0 += zr[128]; zg1 += zr[129];
            zo0 += zr[192]; zo1 += zr[193];
        }
        float i0 = sigm(zi0), f0 = sigm(zf0), g0 = tanh_fast(zg0), o0 = sigm(zo0);
        float i1 = sigm(zi1), f1 = sigm(zf1), g1 = tanh_fast(zg1), o1 = sigm(zo1);
        cst0 = f0 * cst0 + i0 * g0;
        cst1 = f1 * cst1 + i1 * g1;
        float h0 = o0 * tanh_fast(cst0);
        float h1 = o1 * tanh_fast(cst1);
        ss0 += h0; sq0 += h0 * h0; ss1 += h1; sq1 += h1 * h1;

        u32 pk = (u32)__half_as_ushort(__float2half(h0)) |
                 ((u32)__half_as_ushort(__float2half(h1)) << 16);
        u32* dst = (u32*)(hout + (growT + t) * HH + cb * 64) + uh;
        __hip_atomic_store(dst, pk, __ATOMIC_RELAXED, __HIP_MEMORY_SCOPE_AGENT);

        __syncthreads();   // all waves drain vmcnt -> h at LLC before flag
        if (tid == 0)
            __hip_atomic_store(myflag, (u32)(t + 1), __ATOMIC_RELAXED, __HIP_MEMORY_SCOPE_AGENT);
    }

    // ---- fused BN stats ----
    float* red = zbuf;
    red[ub * 64 + 2 * uh] = ss0;
    red[ub * 64 + 2 * uh + 1] = ss1;
    __syncthreads();
    if (tid < 64) {
        float s = 0.f;
#pragma unroll
        for (int b = 0; b < 16; ++b) s += red[b * 64 + tid];
        atomicAdd(&accum[cb * 64 + tid], s);
    }
    __syncthreads();
    red[ub * 64 + 2 * uh] = sq0;
    red[ub * 64 + 2 * uh + 1] = sq1;
    __syncthreads();
    if (tid < 64) {
        float s = 0.f;
#pragma unroll
        for (int b = 0; b < 16; ++b) s += red[b * 64 + tid];
        atomicAdd(&accum[HH + cb * 64 + tid], s);
    }
}

__global__ __launch_bounds__(512) void bn_finalize(
    const float* __restrict__ accum, const float* __restrict__ gamma,
    const float* __restrict__ beta, float* __restrict__ s, float* __restrict__ t)
{
    int j = threadIdx.x;
    const float inv = 1.0f / (float)(BB * TT);
    float m = accum[j] * inv;
    float v = accum[HH + j] * inv - m * m;
    float scv = gamma[j] * rsqrtf(v + 1e-5f);
    s[j] = scv;
    t[j] = beta[j] - m * scv;
}

// ---------------------------------------------------------------------------
// Head: out[m] = relu(bn(h2[m,:]) @ Wd1 + bd1) @ Wd2 + bd2
// ---------------------------------------------------------------------------
__global__ __launch_bounds__(256) void head_kernel(
    const __half* __restrict__ h2, const float* __restrict__ s2,
    const float* __restrict__ t2, const float* __restrict__ Wd1,
    const float* __restrict__ bd1, const float* __restrict__ Wd2,
    const float* __restrict__ bd2, float* __restrict__ out)
{
    const int tid = threadIdx.x;
    const int j = tid & 15;
    const int row = blockIdx.x * 16 + (tid >> 4);
    const __half* hr = h2 + (size_t)row * HH;
    float acc = 0.0f;
    for (int k = 0; k < HH; ++k) {
        float a = __half2float(hr[k]) * s2[k] + t2[k];
        acc += a * Wd1[k * 16 + j];
    }
    float r = fmaxf(acc + bd1[j], 0.0f);
    float v = r * Wd2[j];
#pragma unroll
    for (int off = 8; off; off >>= 1) v += __shfl_down(v, off, 16);
    if (j == 0) out[row] = v + bd2[0];
}

// ---------------------------------------------------------------------------
extern "C" void kernel_launch(void* const* d_in, const int* in_sizes, int n_in,
                              void* d_out, int out_size, void* d_ws, size_t ws_size,
                              hipStream_t stream)
{
    const float* x   = (const float*)d_in[0];
    const float* Wx1 = (const float*)d_in[1];
    const float* Wh1 = (const float*)d_in[2];
    const float* b1  = (const float*)d_in[3];
    const float* g1  = (const float*)d_in[4];
    const float* be1 = (const float*)d_in[5];
    const float* Wx2 = (const float*)d_in[6];
    const float* Wh2 = (const float*)d_in[7];
    const float* b2  = (const float*)d_in[8];
    const float* g2  = (const float*)d_in[9];
    const float* be2 = (const float*)d_in[10];
    const float* Wd1 = (const float*)d_in[11];
    const float* bd1 = (const float*)d_in[12];
    const float* Wd2 = (const float*)d_in[13];
    const float* bd2 = (const float*)d_in[14];
    float* out = (float*)d_out;

    char* ws = (char*)d_ws;
    __half* xW    = (__half*)(ws);                   // 128 MiB  [B*T, 2048]
    __half* h1    = (__half*)(ws + 134217728);       // 32 MiB   [B*T, 512]
    __half* h2    = (__half*)(ws + 167772160);       // 32 MiB
    float*  accum = (float*) (ws + 201326592);       // 2048 f32
    u32*    cnt   = (u32*)   (ws + 201334784);       // 2048 u32 barrier flags
    float*  s1    = (float*) (ws + 201342976);
    float*  t1    = s1 + HH;
    float*  s2    = t1 + HH;
    float*  t2    = s2 + HH;

    const int M = BB * TT;  // 32768

    zero_init<<<1, 256, 0, stream>>>(accum, cnt);

    gemm_mfma<false, false><<<dim3(16, M / 128), 256, 0, stream>>>(
        x, Wx1, b1, nullptr, nullptr, xW, FF);

    lstm_scan_mfma<<<32, 512, 0, stream>>>(xW, Wh1, h1, cnt, accum);
    bn_finalize<<<1, 512, 0, stream>>>(accum, g1, be1, s1, t1);

    gemm_mfma<true, true><<<dim3(16, M / 128), 256, 0, stream>>>(
        h1, Wx2, b2, s1, t1, xW, HH);

    lstm_scan_mfma<<<32, 512, 0, stream>>>(xW, Wh2, h2, cnt + 1024, accum + 1024);
    bn_finalize<<<1, 512, 0, stream>>>(accum + 1024, g2, be2, s2, t2);

    head_kernel<<<M / 16, 256, 0, stream>>>(h2, s2, t2, Wd1, bd1, Wd2, bd2, out);
}